// Round 2
// baseline (131.588 us; speedup 1.0000x reference)
//
#include <hip/hip_runtime.h>
#include <hip/hip_bf16.h>

typedef __attribute__((ext_vector_type(4))) float f32x4;
typedef __attribute__((ext_vector_type(8))) short bf16x8;
typedef unsigned int u32;

__device__ __forceinline__ short f2bf(float f) {
    u32 u = __builtin_bit_cast(u32, f);
    u = (u + 0x7FFFu + ((u >> 16) & 1u)) >> 16;
    return (short)u;
}

__device__ __forceinline__ void gload_lds16(const void* g, void* l) {
    __builtin_amdgcn_global_load_lds(
        (__attribute__((address_space(1))) u32*)g,
        (__attribute__((address_space(3))) u32*)l,
        16, 0, 0);
}

// ---------- transpose + fp32->bf16 convert: src[R][C] -> dst[C][R] ----------
__global__ void transpose_cvt(const float* __restrict__ src, short* __restrict__ dst,
                              int R, int C) {
    __shared__ float tile[32][33];
    const int c0 = blockIdx.x * 32, r0 = blockIdx.y * 32;
    const size_t base = (size_t)blockIdx.z * R * C;
    const int tx = threadIdx.x, ty = threadIdx.y;
#pragma unroll
    for (int i = 0; i < 32; i += 8)
        tile[ty + i][tx] = src[base + (size_t)(r0 + ty + i) * C + c0 + tx];
    __syncthreads();
#pragma unroll
    for (int i = 0; i < 32; i += 8)
        dst[base + (size_t)(c0 + ty + i) * R + r0 + tx] = f2bf(tile[tx][ty + i]);
}

// ---------- bf16 transpose: src[R][C] -> dst[C][R] (per-z batch) ----------
__global__ void transpose_bf(const short* __restrict__ src, short* __restrict__ dst,
                             int R, int C) {
    __shared__ short tile[32][33];
    const int c0 = blockIdx.x * 32, r0 = blockIdx.y * 32;
    const size_t base = (size_t)blockIdx.z * R * C;
    const int tx = threadIdx.x, ty = threadIdx.y;
#pragma unroll
    for (int i = 0; i < 32; i += 8)
        tile[ty + i][tx] = src[base + (size_t)(r0 + ty + i) * C + c0 + tx];
    __syncthreads();
#pragma unroll
    for (int i = 0; i < 32; i += 8)
        dst[base + (size_t)(c0 + ty + i) * R + r0 + tx] = tile[tx][ty + i];
}

// ---------- GEMM1: qkv = xT @ w_qkv + b_qkv, scatter to Q(,scaled)/K/V ----------
// At = xT bf16 [8192][512], Bt = wqkvT bf16 [1536][512]
__global__ __launch_bounds__(256, 2) void gemm_qkv(
    const short* __restrict__ At, const short* __restrict__ Bt,
    const float* __restrict__ bias,
    short* __restrict__ Qo, short* __restrict__ Ko, short* __restrict__ Vo) {
    __shared__ short As[128 * 32];
    __shared__ short Bs[128 * 32];
    const int t = threadIdx.x, w = t >> 6, l = t & 63;
    const int n0 = blockIdx.x * 128, m0 = blockIdx.y * 128;
    const int ar0 = t >> 2, ac = (t & 3) * 8;   // staging row/col
    f32x4 acc[4][4] = {};
    const int wmr = (w >> 1) * 64, wnr = (w & 1) * 64;
    const int lg = l >> 4, li = l & 15;
    for (int k0 = 0; k0 < 512; k0 += 32) {
        gload_lds16(At + (size_t)(m0 + ar0) * 512 + k0 + ac, As + t * 8);
        gload_lds16(At + (size_t)(m0 + ar0 + 64) * 512 + k0 + ac, As + (t + 256) * 8);
        gload_lds16(Bt + (size_t)(n0 + ar0) * 512 + k0 + ac, Bs + t * 8);
        gload_lds16(Bt + (size_t)(n0 + ar0 + 64) * 512 + k0 + ac, Bs + (t + 256) * 8);
        __syncthreads();
        bf16x8 af[4], bf_[4];
#pragma unroll
        for (int mt = 0; mt < 4; ++mt)
            af[mt] = *(const bf16x8*)&As[(wmr + mt * 16 + li) * 32 + lg * 8];
#pragma unroll
        for (int nt = 0; nt < 4; ++nt)
            bf_[nt] = *(const bf16x8*)&Bs[(wnr + nt * 16 + li) * 32 + lg * 8];
#pragma unroll
        for (int mt = 0; mt < 4; ++mt)
#pragma unroll
            for (int nt = 0; nt < 4; ++nt)
                acc[mt][nt] = __builtin_amdgcn_mfma_f32_16x16x32_bf16(af[mt], bf_[nt], acc[mt][nt], 0, 0, 0);
        __syncthreads();
    }
    // epilogue: col = n0+wnr+nt*16+li in [0,1536). 64-col chunk uniform in (t,h).
    const int colbase = n0 + wnr;
    const int tsel = colbase >> 9;
    const int h = (colbase & 511) >> 6;
    short* __restrict__ dst = (tsel == 0) ? Qo : ((tsel == 1) ? Ko : Vo);
    const float scale = (tsel == 0) ? 0.125f : 1.0f;
#pragma unroll
    for (int nt = 0; nt < 4; ++nt) {
        const int d = nt * 16 + li;
        const float bv = bias[colbase + d];
#pragma unroll
        for (int mt = 0; mt < 4; ++mt) {
            const int rowb = m0 + wmr + mt * 16 + lg * 4;
#pragma unroll
            for (int r = 0; r < 4; ++r) {
                const int row = rowb + r;
                const int bb = row >> 10, np = row & 1023;
                const float v = (acc[mt][nt][r] + bv) * scale;
                dst[((size_t)(bb * 8 + h) * 1024 + np) * 64 + d] = f2bf(v);
            }
        }
    }
}

// ---------- attention: per (bh, 64-query tile), flash over 64-key tiles ----------
// Qg,Kg: bf16 [BH][1024][64]  (Q pre-scaled by 0.125), Vtg: bf16 [BH][64][1024]
// Og: bf16 [8192][512]
__global__ __launch_bounds__(256, 2) void attn_kernel(
    const short* __restrict__ Qg, const short* __restrict__ Kg,
    const short* __restrict__ Vtg, short* __restrict__ Og) {
    __shared__ short Ks[64 * 64];
    __shared__ short Vts[64 * 64];
    __shared__ short Ps[4][16 * 64];
    const int t = threadIdx.x, w = t >> 6, l = t & 63, lg = l >> 4, li = l & 15;
    const int bh = blockIdx.y;
    const int n0 = blockIdx.x * 64;
    const int b = bh >> 3, h = bh & 7;

    // Q fragments (A operand rows = l&15), held for all key tiles
    const int qa = n0 + w * 16 + li;
    const size_t qbase = ((size_t)bh * 1024 + qa) * 64;
    const bf16x8 aq0 = *(const bf16x8*)&Qg[qbase + lg * 8];
    const bf16x8 aq1 = *(const bf16x8*)&Qg[qbase + 32 + lg * 8];

    f32x4 oacc[4] = {};
    float mrow[4] = {-1e30f, -1e30f, -1e30f, -1e30f};
    float lrow[4] = {0.f, 0.f, 0.f, 0.f};

    const int krow0 = t >> 3, kcol = (t & 7) * 8;  // staging
    for (int kt = 0; kt < 1024; kt += 64) {
        gload_lds16(Kg + ((size_t)bh * 1024 + kt + krow0) * 64 + kcol, Ks + t * 8);
        gload_lds16(Kg + ((size_t)bh * 1024 + kt + krow0 + 32) * 64 + kcol, Ks + (t + 256) * 8);
        gload_lds16(Vtg + ((size_t)bh * 64 + krow0) * 1024 + kt + kcol, Vts + t * 8);
        gload_lds16(Vtg + ((size_t)bh * 64 + krow0 + 32) * 1024 + kt + kcol, Vts + (t + 256) * 8);
        __syncthreads();

        // S = Q K^T  (16 queries x 64 keys per wave)
        f32x4 s[4];
#pragma unroll
        for (int nt = 0; nt < 4; ++nt) {
            const bf16x8 bk0 = *(const bf16x8*)&Ks[(nt * 16 + li) * 64 + lg * 8];
            const bf16x8 bk1 = *(const bf16x8*)&Ks[(nt * 16 + li) * 64 + 32 + lg * 8];
            f32x4 z = {};
            z = __builtin_amdgcn_mfma_f32_16x16x32_bf16(aq0, bk0, z, 0, 0, 0);
            z = __builtin_amdgcn_mfma_f32_16x16x32_bf16(aq1, bk1, z, 0, 0, 0);
            s[nt] = z;
        }
        // online softmax; D-row of reg r is query lg*4+r, col = li
        float mnew[4], sc[4];
#pragma unroll
        for (int r = 0; r < 4; ++r) {
            float v = fmaxf(fmaxf(s[0][r], s[1][r]), fmaxf(s[2][r], s[3][r]));
#pragma unroll
            for (int mm = 8; mm >= 1; mm >>= 1) v = fmaxf(v, __shfl_xor(v, mm));
            mnew[r] = fmaxf(mrow[r], v);
            sc[r] = __expf(mrow[r] - mnew[r]);
            mrow[r] = mnew[r];
        }
        float ps[4] = {0.f, 0.f, 0.f, 0.f};
#pragma unroll
        for (int nt = 0; nt < 4; ++nt)
#pragma unroll
            for (int r = 0; r < 4; ++r) {
                float p = __expf(s[nt][r] - mnew[r]);
                s[nt][r] = p;
                ps[r] += p;
            }
#pragma unroll
        for (int r = 0; r < 4; ++r) {
            float v = ps[r];
#pragma unroll
            for (int mm = 8; mm >= 1; mm >>= 1) v += __shfl_xor(v, mm);
            lrow[r] = lrow[r] * sc[r] + v;
        }
#pragma unroll
        for (int dt = 0; dt < 4; ++dt)
#pragma unroll
            for (int r = 0; r < 4; ++r) oacc[dt][r] *= sc[r];

        // P -> LDS (row-major [16 q][64 k]) then A-frags
#pragma unroll
        for (int nt = 0; nt < 4; ++nt)
#pragma unroll
            for (int r = 0; r < 4; ++r)
                Ps[w][(lg * 4 + r) * 64 + nt * 16 + li] = f2bf(s[nt][r]);
        const bf16x8 pa0 = *(const bf16x8*)&Ps[w][li * 64 + lg * 8];
        const bf16x8 pa1 = *(const bf16x8*)&Ps[w][li * 64 + 32 + lg * 8];
#pragma unroll
        for (int dt = 0; dt < 4; ++dt) {
            const bf16x8 bv0 = *(const bf16x8*)&Vts[(dt * 16 + li) * 64 + lg * 8];
            const bf16x8 bv1 = *(const bf16x8*)&Vts[(dt * 16 + li) * 64 + 32 + lg * 8];
            oacc[dt] = __builtin_amdgcn_mfma_f32_16x16x32_bf16(pa0, bv0, oacc[dt], 0, 0, 0);
            oacc[dt] = __builtin_amdgcn_mfma_f32_16x16x32_bf16(pa1, bv1, oacc[dt], 0, 0, 0);
        }
        __syncthreads();
    }
    // normalize + store to O [8192][512] at col h*64+d
#pragma unroll
    for (int r = 0; r < 4; ++r) {
        const float inv = 1.f / lrow[r];
        const int qq = n0 + w * 16 + lg * 4 + r;
#pragma unroll
        for (int dt = 0; dt < 4; ++dt)
            Og[(size_t)(b * 1024 + qq) * 512 + h * 64 + dt * 16 + li] = f2bf(oacc[dt][r] * inv);
    }
}

// ---------- GEMM2: outT[c][n] = wprojT[c][:] . O[n][:] + b_proj[c] ----------
// At = wprojT bf16 [512][512], Bsrc = O bf16 [8192][512], out fp32 (B,C,N)
__global__ __launch_bounds__(256, 2) void gemm_proj(
    const short* __restrict__ At, const short* __restrict__ Bsrc,
    const float* __restrict__ bias, float* __restrict__ out) {
    __shared__ short As[128 * 32];
    __shared__ short Bs[128 * 32];
    const int t = threadIdx.x, w = t >> 6, l = t & 63;
    const int n0 = blockIdx.x * 128, m0 = blockIdx.y * 128, bz = blockIdx.z;
    const int ar0 = t >> 2, ac = (t & 3) * 8;
    f32x4 acc[4][4] = {};
    const int wmr = (w >> 1) * 64, wnr = (w & 1) * 64;
    const int lg = l >> 4, li = l & 15;
    for (int k0 = 0; k0 < 512; k0 += 32) {
        gload_lds16(At + (size_t)(m0 + ar0) * 512 + k0 + ac, As + t * 8);
        gload_lds16(At + (size_t)(m0 + ar0 + 64) * 512 + k0 + ac, As + (t + 256) * 8);
        gload_lds16(Bsrc + ((size_t)bz * 1024 + n0 + ar0) * 512 + k0 + ac, Bs + t * 8);
        gload_lds16(Bsrc + ((size_t)bz * 1024 + n0 + ar0 + 64) * 512 + k0 + ac, Bs + (t + 256) * 8);
        __syncthreads();
        bf16x8 af[4], bf_[4];
#pragma unroll
        for (int mt = 0; mt < 4; ++mt)
            af[mt] = *(const bf16x8*)&As[(wmr + mt * 16 + li) * 32 + lg * 8];
#pragma unroll
        for (int nt = 0; nt < 4; ++nt)
            bf_[nt] = *(const bf16x8*)&Bs[(wnr + nt * 16 + li) * 32 + lg * 8];
#pragma unroll
        for (int mt = 0; mt < 4; ++mt)
#pragma unroll
            for (int nt = 0; nt < 4; ++nt)
                acc[mt][nt] = __builtin_amdgcn_mfma_f32_16x16x32_bf16(af[mt], bf_[nt], acc[mt][nt], 0, 0, 0);
        __syncthreads();
    }
#pragma unroll
    for (int mt = 0; mt < 4; ++mt)
#pragma unroll
        for (int r = 0; r < 4; ++r) {
            const int c = m0 + wmr + mt * 16 + lg * 4 + r;
            const float bv = bias[c];
#pragma unroll
            for (int nt = 0; nt < 4; ++nt) {
                const int col = n0 + wnr + nt * 16 + li;
                out[(size_t)(bz * 512 + c) * 1024 + col] = acc[mt][nt][r] + bv;
            }
        }
}

extern "C" void kernel_launch(void* const* d_in, const int* in_sizes, int n_in,
                              void* d_out, int out_size, void* d_ws, size_t ws_size,
                              hipStream_t stream) {
    const float* x      = (const float*)d_in[0];   // (8,512,1024)
    const float* w_qkv  = (const float*)d_in[1];   // (512,1536)
    const float* b_qkv  = (const float*)d_in[2];   // (1536)
    const float* w_proj = (const float*)d_in[3];   // (512,512)
    const float* b_proj = (const float*)d_in[4];   // (512)
    float* out = (float*)d_out;                    // (8,512,1024)

    char* ws = (char*)d_ws;
    size_t off = 0;
    auto carve = [&](size_t bytes) {
        void* p = ws + off;
        off = (off + bytes + 255) & ~(size_t)255;
        return p;
    };
    short* xT     = (short*)carve((size_t)8 * 1024 * 512 * 2);
    short* wqkvT  = (short*)carve((size_t)1536 * 512 * 2);
    short* wprojT = (short*)carve((size_t)512 * 512 * 2);
    short* Q      = (short*)carve((size_t)8 * 8 * 1024 * 64 * 2);
    short* K      = (short*)carve((size_t)8 * 8 * 1024 * 64 * 2);
    short* V      = (short*)carve((size_t)8 * 8 * 1024 * 64 * 2);
    short* Vt     = (short*)carve((size_t)8 * 8 * 64 * 1024 * 2);
    short* O      = (short*)carve((size_t)8 * 1024 * 512 * 2);

    dim3 tb(32, 8);
    transpose_cvt<<<dim3(1536 / 32, 512 / 32, 1), tb, 0, stream>>>(w_qkv, wqkvT, 512, 1536);
    transpose_cvt<<<dim3(512 / 32, 512 / 32, 1), tb, 0, stream>>>(w_proj, wprojT, 512, 512);
    transpose_cvt<<<dim3(1024 / 32, 512 / 32, 8), tb, 0, stream>>>(x, xT, 512, 1024);
    gemm_qkv<<<dim3(12, 64), 256, 0, stream>>>(xT, wqkvT, b_qkv, Q, K, V);
    transpose_bf<<<dim3(64 / 32, 1024 / 32, 64), tb, 0, stream>>>(V, Vt, 1024, 64);
    attn_kernel<<<dim3(16, 64), 256, 0, stream>>>(Q, K, Vt, O);
    gemm_proj<<<dim3(8, 4, 8), 256, 0, stream>>>(wprojT, O, b_proj, out);
}

// Round 4
// 111.146 us; speedup vs baseline: 1.1839x; 1.1839x over previous
//
#include <hip/hip_runtime.h>
#include <hip/hip_bf16.h>

typedef __attribute__((ext_vector_type(4))) float f32x4;
typedef __attribute__((ext_vector_type(8))) short bf16x8;
typedef unsigned int u32;

__device__ __forceinline__ short f2bf(float f) {
    u32 u = __builtin_bit_cast(u32, f);
    u = (u + 0x7FFFu + ((u >> 16) & 1u)) >> 16;
    return (short)u;
}

__device__ __forceinline__ void gload_lds16(const void* g, void* l) {
    __builtin_amdgcn_global_load_lds(
        (__attribute__((address_space(1))) u32*)g,
        (__attribute__((address_space(3))) u32*)l,
        16, 0, 0);
}

// ---------- transpose + fp32->bf16 convert: src[R][C] -> dst[C][R] ----------
__global__ void transpose_cvt(const float* __restrict__ src, short* __restrict__ dst,
                              int R, int C) {
    __shared__ float tile[32][33];
    const int c0 = blockIdx.x * 32, r0 = blockIdx.y * 32;
    const size_t base = (size_t)blockIdx.z * R * C;
    const int tx = threadIdx.x, ty = threadIdx.y;
#pragma unroll
    for (int i = 0; i < 32; i += 8)
        tile[ty + i][tx] = src[base + (size_t)(r0 + ty + i) * C + c0 + tx];
    __syncthreads();
#pragma unroll
    for (int i = 0; i < 32; i += 8)
        dst[base + (size_t)(c0 + ty + i) * R + r0 + tx] = f2bf(tile[tx][ty + i]);
}

// ---------- bf16 transpose: src[R][C] -> dst[C][R] (per-z batch) ----------
__global__ void transpose_bf(const short* __restrict__ src, short* __restrict__ dst,
                             int R, int C) {
    __shared__ short tile[32][33];
    const int c0 = blockIdx.x * 32, r0 = blockIdx.y * 32;
    const size_t base = (size_t)blockIdx.z * R * C;
    const int tx = threadIdx.x, ty = threadIdx.y;
#pragma unroll
    for (int i = 0; i < 32; i += 8)
        tile[ty + i][tx] = src[base + (size_t)(r0 + ty + i) * C + c0 + tx];
    __syncthreads();
#pragma unroll
    for (int i = 0; i < 32; i += 8)
        dst[base + (size_t)(c0 + ty + i) * R + r0 + tx] = tile[tx][ty + i];
}

// ---------- GEMM1: qkv = xT @ w_qkv + b_qkv, scatter to Q(,scaled)/K/V ----------
// At = xT bf16 [8192][512], Bt = wqkvT bf16 [1536][512]
// LDS tiles [128 rows][4 chunks of 16B]; chunk swizzle key (row>>1)&3 (2-row pairs)
__global__ __launch_bounds__(256, 2) void gemm_qkv(
    const short* __restrict__ At, const short* __restrict__ Bt,
    const float* __restrict__ bias,
    short* __restrict__ Qo, short* __restrict__ Ko, short* __restrict__ Vo) {
    __shared__ short As[2][128 * 32];
    __shared__ short Bs[2][128 * 32];
    const int t = threadIdx.x, w = t >> 6, l = t & 63;
    const int n0 = blockIdx.x * 128, m0 = blockIdx.y * 128;
    const int srow = t >> 2;                        // staging row 0..63
    const int sgc = (t & 3) ^ ((t >> 3) & 3);       // pre-swizzled source chunk
    f32x4 acc[4][4] = {};
    const int wmr = (w >> 1) * 64, wnr = (w & 1) * 64;
    const int lg = l >> 4, li = l & 15;
    const int rc = (lg ^ ((li >> 1) & 3)) * 8;      // swizzled read chunk (shorts)

    auto stage = [&](int buf, int k0) {
        gload_lds16(At + (size_t)(m0 + srow) * 512 + k0 + sgc * 8, As[buf] + t * 8);
        gload_lds16(At + (size_t)(m0 + srow + 64) * 512 + k0 + sgc * 8, As[buf] + (t + 256) * 8);
        gload_lds16(Bt + (size_t)(n0 + srow) * 512 + k0 + sgc * 8, Bs[buf] + t * 8);
        gload_lds16(Bt + (size_t)(n0 + srow + 64) * 512 + k0 + sgc * 8, Bs[buf] + (t + 256) * 8);
    };

    stage(0, 0);
    __syncthreads();
    for (int kt = 0; kt < 16; ++kt) {
        const int cur = kt & 1;
        if (kt + 1 < 16) stage(cur ^ 1, (kt + 1) * 32);
        bf16x8 af[4], bf_[4];
#pragma unroll
        for (int mt = 0; mt < 4; ++mt)
            af[mt] = *(const bf16x8*)&As[cur][(wmr + mt * 16 + li) * 32 + rc];
#pragma unroll
        for (int nt = 0; nt < 4; ++nt)
            bf_[nt] = *(const bf16x8*)&Bs[cur][(wnr + nt * 16 + li) * 32 + rc];
#pragma unroll
        for (int mt = 0; mt < 4; ++mt)
#pragma unroll
            for (int nt = 0; nt < 4; ++nt)
                acc[mt][nt] = __builtin_amdgcn_mfma_f32_16x16x32_bf16(af[mt], bf_[nt], acc[mt][nt], 0, 0, 0);
        __syncthreads();
    }
    // epilogue: col = n0+wnr+nt*16+li in [0,1536). 64-col chunk uniform per thread.
    const int colbase = n0 + wnr;
    const int tsel = colbase >> 9;
    const int h = (colbase & 511) >> 6;
    short* __restrict__ dst = (tsel == 0) ? Qo : ((tsel == 1) ? Ko : Vo);
    const float scale = (tsel == 0) ? 0.125f : 1.0f;
#pragma unroll
    for (int nt = 0; nt < 4; ++nt) {
        const int d = nt * 16 + li;
        const float bv = bias[colbase + d];
#pragma unroll
        for (int mt = 0; mt < 4; ++mt) {
            const int rowb = m0 + wmr + mt * 16 + lg * 4;
#pragma unroll
            for (int r = 0; r < 4; ++r) {
                const int row = rowb + r;
                const int bb = row >> 10, np = row & 1023;
                const float v = (acc[mt][nt][r] + bv) * scale;
                dst[((size_t)(bb * 8 + h) * 1024 + np) * 64 + d] = f2bf(v);
            }
        }
    }
}

// ---------- attention: flash over 64-key tiles, swizzled LDS, dbuf+syncthreads ----------
// Qg,Kg: bf16 [BH][1024][64] (Q pre-scaled), Vtg: bf16 [BH][64][1024], Og: bf16 [8192][512]
// K/Vt LDS: [64 rows][8 chunks of 16B], chunk swizzle key row&7. P: [16][8 chunks], same key.
__global__ __launch_bounds__(256, 2) void attn_kernel(
    const short* __restrict__ Qg, const short* __restrict__ Kg,
    const short* __restrict__ Vtg, short* __restrict__ Og) {
    __shared__ short Ks[2][64 * 64];
    __shared__ short Vts[2][64 * 64];
    __shared__ short Ps[4][16 * 64];
    const int t = threadIdx.x, w = t >> 6, l = t & 63, lg = l >> 4, li = l & 15;
    const int n0 = blockIdx.x * 64;
    const int bh = blockIdx.y;
    const int b = bh >> 3, h = bh & 7;

    // Q fragments (A rows = li), held across all key tiles
    const int qa = n0 + w * 16 + li;
    const size_t qbase = ((size_t)bh * 1024 + qa) * 64;
    const bf16x8 aq0 = *(const bf16x8*)&Qg[qbase + lg * 8];
    const bf16x8 aq1 = *(const bf16x8*)&Qg[qbase + 32 + lg * 8];

    f32x4 oacc[4] = {};
    float mrow[4] = {-1e30f, -1e30f, -1e30f, -1e30f};
    float lrow[4] = {0.f, 0.f, 0.f, 0.f};

    const int srow = t >> 3;                    // staging row 0..31
    const int sgc = (t & 7) ^ ((t >> 3) & 7);   // pre-swizzled source chunk
    const int kc0 = (lg ^ (li & 7)) * 8;        // swizzled read chunk (shorts): global chunk lg
    const int kc1 = kc0 ^ 32;                   // global chunk lg+4 (XOR chunk-bit 4 -> shorts ^32)

    auto stageKV = [&](int buf, int ktile) {
        const int kt = ktile * 64;
        short* kb = Ks[buf];
        short* vb = Vts[buf];
        gload_lds16(Kg + ((size_t)bh * 1024 + kt + srow) * 64 + sgc * 8, kb + t * 8);
        gload_lds16(Kg + ((size_t)bh * 1024 + kt + srow + 32) * 64 + sgc * 8, kb + (t + 256) * 8);
        gload_lds16(Vtg + ((size_t)bh * 64 + srow) * 1024 + kt + sgc * 8, vb + t * 8);
        gload_lds16(Vtg + ((size_t)bh * 64 + srow + 32) * 1024 + kt + sgc * 8, vb + (t + 256) * 8);
    };

    stageKV(0, 0);
    __syncthreads();
    for (int kt = 0; kt < 16; ++kt) {
        const int cur = kt & 1;
        if (kt + 1 < 16) stageKV(cur ^ 1, kt + 1);
        const short* kb = Ks[cur];
        const short* vb = Vts[cur];

        // S = Q K^T (16 queries x 64 keys per wave)
        f32x4 s[4];
#pragma unroll
        for (int nt = 0; nt < 4; ++nt) {
            const int krow = (nt * 16 + li) * 64;
            const bf16x8 bk0 = *(const bf16x8*)&kb[krow + kc0];
            const bf16x8 bk1 = *(const bf16x8*)&kb[krow + kc1];
            f32x4 z = {};
            z = __builtin_amdgcn_mfma_f32_16x16x32_bf16(aq0, bk0, z, 0, 0, 0);
            z = __builtin_amdgcn_mfma_f32_16x16x32_bf16(aq1, bk1, z, 0, 0, 0);
            s[nt] = z;
        }
        // online softmax; reg r is query lg*4+r, key col = nt*16+li
        float mnew[4], sc[4];
#pragma unroll
        for (int r = 0; r < 4; ++r) {
            float v = fmaxf(fmaxf(s[0][r], s[1][r]), fmaxf(s[2][r], s[3][r]));
#pragma unroll
            for (int mm = 8; mm >= 1; mm >>= 1) v = fmaxf(v, __shfl_xor(v, mm));
            mnew[r] = fmaxf(mrow[r], v);
            sc[r] = __expf(mrow[r] - mnew[r]);
            mrow[r] = mnew[r];
        }
        float ps[4] = {0.f, 0.f, 0.f, 0.f};
#pragma unroll
        for (int nt = 0; nt < 4; ++nt)
#pragma unroll
            for (int r = 0; r < 4; ++r) {
                float p = __expf(s[nt][r] - mnew[r]);
                s[nt][r] = p;
                ps[r] += p;
            }
#pragma unroll
        for (int r = 0; r < 4; ++r) {
            float v = ps[r];
#pragma unroll
            for (int mm = 8; mm >= 1; mm >>= 1) v += __shfl_xor(v, mm);
            lrow[r] = lrow[r] * sc[r] + v;
        }
#pragma unroll
        for (int dt = 0; dt < 4; ++dt)
#pragma unroll
            for (int r = 0; r < 4; ++r) oacc[dt][r] *= sc[r];

        // P -> LDS (swizzled [16 q][8 chunks]), wave-private
#pragma unroll
        for (int nt = 0; nt < 4; ++nt)
#pragma unroll
            for (int r = 0; r < 4; ++r) {
                const int prow = lg * 4 + r;
                const int pchunk = (nt * 2 + (li >> 3)) ^ (prow & 7);
                Ps[w][prow * 64 + pchunk * 8 + (li & 7)] = f2bf(s[nt][r]);
            }
        const bf16x8 pa0 = *(const bf16x8*)&Ps[w][li * 64 + kc0];
        const bf16x8 pa1 = *(const bf16x8*)&Ps[w][li * 64 + kc1];
#pragma unroll
        for (int dt = 0; dt < 4; ++dt) {
            const int vrow = (dt * 16 + li) * 64;
            const bf16x8 bv0 = *(const bf16x8*)&vb[vrow + kc0];
            const bf16x8 bv1 = *(const bf16x8*)&vb[vrow + kc1];
            oacc[dt] = __builtin_amdgcn_mfma_f32_16x16x32_bf16(pa0, bv0, oacc[dt], 0, 0, 0);
            oacc[dt] = __builtin_amdgcn_mfma_f32_16x16x32_bf16(pa1, bv1, oacc[dt], 0, 0, 0);
        }
        __syncthreads();
    }
    // normalize + store to O [8192][512] at col h*64+d
#pragma unroll
    for (int r = 0; r < 4; ++r) {
        const float inv = 1.f / lrow[r];
        const int qq = n0 + w * 16 + lg * 4 + r;
#pragma unroll
        for (int dt = 0; dt < 4; ++dt)
            Og[(size_t)(b * 1024 + qq) * 512 + h * 64 + dt * 16 + li] = f2bf(oacc[dt][r] * inv);
    }
}

// ---------- GEMM2: outT[c][n] = wprojT[c][:] . O[n][:] + b_proj[c] ----------
__global__ __launch_bounds__(256, 2) void gemm_proj(
    const short* __restrict__ At, const short* __restrict__ Bsrc,
    const float* __restrict__ bias, float* __restrict__ out) {
    __shared__ short As[2][128 * 32];
    __shared__ short Bs[2][128 * 32];
    const int t = threadIdx.x, w = t >> 6, l = t & 63;
    const int n0 = blockIdx.x * 128, m0 = blockIdx.y * 128, bz = blockIdx.z;
    const int srow = t >> 2;
    const int sgc = (t & 3) ^ ((t >> 3) & 3);
    f32x4 acc[4][4] = {};
    const int wmr = (w >> 1) * 64, wnr = (w & 1) * 64;
    const int lg = l >> 4, li = l & 15;
    const int rc = (lg ^ ((li >> 1) & 3)) * 8;

    auto stage = [&](int buf, int k0) {
        gload_lds16(At + (size_t)(m0 + srow) * 512 + k0 + sgc * 8, As[buf] + t * 8);
        gload_lds16(At + (size_t)(m0 + srow + 64) * 512 + k0 + sgc * 8, As[buf] + (t + 256) * 8);
        gload_lds16(Bsrc + ((size_t)bz * 1024 + n0 + srow) * 512 + k0 + sgc * 8, Bs[buf] + t * 8);
        gload_lds16(Bsrc + ((size_t)bz * 1024 + n0 + srow + 64) * 512 + k0 + sgc * 8, Bs[buf] + (t + 256) * 8);
    };

    stage(0, 0);
    __syncthreads();
    for (int kt = 0; kt < 16; ++kt) {
        const int cur = kt & 1;
        if (kt + 1 < 16) stage(cur ^ 1, (kt + 1) * 32);
        bf16x8 af[4], bf_[4];
#pragma unroll
        for (int mt = 0; mt < 4; ++mt)
            af[mt] = *(const bf16x8*)&As[cur][(wmr + mt * 16 + li) * 32 + rc];
#pragma unroll
        for (int nt = 0; nt < 4; ++nt)
            bf_[nt] = *(const bf16x8*)&Bs[cur][(wnr + nt * 16 + li) * 32 + rc];
#pragma unroll
        for (int mt = 0; mt < 4; ++mt)
#pragma unroll
            for (int nt = 0; nt < 4; ++nt)
                acc[mt][nt] = __builtin_amdgcn_mfma_f32_16x16x32_bf16(af[mt], bf_[nt], acc[mt][nt], 0, 0, 0);
        __syncthreads();
    }
#pragma unroll
    for (int mt = 0; mt < 4; ++mt)
#pragma unroll
        for (int r = 0; r < 4; ++r) {
            const int c = m0 + wmr + mt * 16 + lg * 4 + r;
            const float bv = bias[c];
#pragma unroll
            for (int nt = 0; nt < 4; ++nt) {
                const int col = n0 + wnr + nt * 16 + li;
                out[(size_t)(bz * 512 + c) * 1024 + col] = acc[mt][nt][r] + bv;
            }
        }
}

extern "C" void kernel_launch(void* const* d_in, const int* in_sizes, int n_in,
                              void* d_out, int out_size, void* d_ws, size_t ws_size,
                              hipStream_t stream) {
    const float* x      = (const float*)d_in[0];   // (8,512,1024)
    const float* w_qkv  = (const float*)d_in[1];   // (512,1536)
    const float* b_qkv  = (const float*)d_in[2];   // (1536)
    const float* w_proj = (const float*)d_in[3];   // (512,512)
    const float* b_proj = (const float*)d_in[4];   // (512)
    float* out = (float*)d_out;                    // (8,512,1024)

    char* ws = (char*)d_ws;
    size_t off = 0;
    auto carve = [&](size_t bytes) {
        void* p = ws + off;
        off = (off + bytes + 255) & ~(size_t)255;
        return p;
    };
    short* xT     = (short*)carve((size_t)8 * 1024 * 512 * 2);
    short* wqkvT  = (short*)carve((size_t)1536 * 512 * 2);
    short* wprojT = (short*)carve((size_t)512 * 512 * 2);
    short* Q      = (short*)carve((size_t)8 * 8 * 1024 * 64 * 2);
    short* K      = (short*)carve((size_t)8 * 8 * 1024 * 64 * 2);
    short* V      = (short*)carve((size_t)8 * 8 * 1024 * 64 * 2);
    short* Vt     = (short*)carve((size_t)8 * 8 * 64 * 1024 * 2);
    short* O      = (short*)carve((size_t)8 * 1024 * 512 * 2);

    dim3 tb(32, 8);
    transpose_cvt<<<dim3(1536 / 32, 512 / 32, 1), tb, 0, stream>>>(w_qkv, wqkvT, 512, 1536);
    transpose_cvt<<<dim3(512 / 32, 512 / 32, 1), tb, 0, stream>>>(w_proj, wprojT, 512, 512);
    transpose_cvt<<<dim3(1024 / 32, 512 / 32, 8), tb, 0, stream>>>(x, xT, 512, 1024);
    gemm_qkv<<<dim3(12, 64), 256, 0, stream>>>(xT, wqkvT, b_qkv, Q, K, V);
    transpose_bf<<<dim3(64 / 32, 1024 / 32, 64), tb, 0, stream>>>(V, Vt, 1024, 64);
    attn_kernel<<<dim3(16, 64), 256, 0, stream>>>(Q, K, Vt, O);
    gemm_proj<<<dim3(8, 4, 8), 256, 0, stream>>>(wprojT, O, b_proj, out);
}